// Round 7
// baseline (32.923 us; speedup 1.0000x reference)
//
#include <hip/hip_runtime.h>

// PSANet COLLECT forward, N=1, H=W=60.
//   out[oh*60+ow][h][w] = x[(oh+59-h)*119 + (ow+59-w)][h][w]
//
// One WG per (oh, h-pair) -- 1800 WGs, 512 threads. Trimmed-parallelogram
// reads, compact LDS scatter lds[hh][ow*60+w] (ow = b+w-59), float4
// contiguous 480 B nontemporal stores per output channel.
//
// R7 change vs R6: deep per-thread MLP in phase 1. Stage A issues all 7
// predicated global_load_dwordx4 into registers (statically unrolled, no
// intervening LDS ops -> back-to-back vmem issue, 7 outstanding/thread);
// stage B scatters from registers to LDS. Loads nontemporal (zero reuse:
// every fetched line's non-segment bytes are provably dead).

#define CH_STRIDE 3600   // H*W floats per channel

typedef float f32x4 __attribute__((ext_vector_type(4)));

__global__ __launch_bounds__(512) void psa_collect_kernel(
    const float* __restrict__ x, float* __restrict__ out) {

    __shared__ float lds[2][3600];    // 28.8 KB, compact parallelogram

    // 2D-tiled XCD swizzle: 1800 = 8 XCD-chunks x (15 oh x 15 hp).
    const int xcd = blockIdx.x & 7;
    const int t   = blockIdx.x >> 3;
    const int ti  = t / 15;
    const int tj  = t - ti * 15;
    const int oh  = (xcd >> 1) * 15 + ti;    // [0,60)
    const int hp  = (xcd & 1) * 15 + tj;     // [0,30)
    const int h0  = hp * 2;
    const int tid = threadIdx.x;

    // Slab base pointers for the two h rows (channel row a = oh+59-h).
    const float* src0 = x + (size_t)(oh + 59 - h0) * 119 * CH_STRIDE + h0 * 60;
    const float* src1 = x + (size_t)(oh + 58 - h0) * 119 * CH_STRIDE + (h0 + 1) * 60;

    // ---- Phase 1, stage A: issue all loads (7-deep MLP) ----
    // Flat float4 index f = tid + 512k over 2 slabs x 119 rows x 15 float4.
    f32x4 vreg[7];
#pragma unroll
    for (int k = 0; k < 7; ++k) {
        const int f  = tid + 512 * k;           // < 3584
        const int hh = (f >= 1785) ? 1 : 0;
        const int g  = f - hh * 1785;
        const int b  = g / 15;                  // channel-grid col
        const int j4 = (g - b * 15) * 4;        // first w of this float4
        const int w0 = (b < 59) ? (59 - b) : 0;
        const int w1 = (b < 59) ? 60 : (119 - b);
        if (f < 3570 && j4 < w1 && j4 + 4 > w0) {
            const float* p = (hh ? src1 : src0) + (size_t)b * CH_STRIDE + j4;
            vreg[k] = __builtin_nontemporal_load(reinterpret_cast<const f32x4*>(p));
        }
    }

    // ---- Phase 1, stage B: scatter registers -> compact LDS ----
#pragma unroll
    for (int k = 0; k < 7; ++k) {
        const int f  = tid + 512 * k;
        const int hh = (f >= 1785) ? 1 : 0;
        const int g  = f - hh * 1785;
        const int b  = g / 15;
        const int j4 = (g - b * 15) * 4;
        const int w0 = (b < 59) ? (59 - b) : 0;
        const int w1 = (b < 59) ? 60 : (119 - b);
        if (f < 3570 && j4 < w1 && j4 + 4 > w0) {
#pragma unroll
            for (int e = 0; e < 4; ++e) {
                const int w = j4 + e;
                const int d = b + w - 59;        // = ow, in [0,60) iff used
                if ((unsigned)d < 60u) lds[hh][d * 60 + w] = vreg[k][e];
            }
        }
    }
    __syncthreads();

    // ---- Phase 2: LDS -> global, 480 B contiguous per output channel ----
    float* dst = out + (size_t)(oh * 60) * CH_STRIDE + h0 * 60;
    for (int m = tid; m < 1800; m += 512) {
        const int ow = m / 30;
        const int r  = m - ow * 30;              // 0..29: (hh, j4)
        const int hh = r / 15;
        const int j4 = (r - hh * 15) * 4;
        const f32x4 v = *reinterpret_cast<const f32x4*>(&lds[hh][ow * 60 + j4]);
        __builtin_nontemporal_store(
            v, reinterpret_cast<f32x4*>(dst + (size_t)ow * CH_STRIDE + hh * 60 + j4));
    }
}

extern "C" void kernel_launch(void* const* d_in, const int* in_sizes, int n_in,
                              void* d_out, int out_size, void* d_ws, size_t ws_size,
                              hipStream_t stream) {
    const float* x = (const float*)d_in[0];
    float* out = (float*)d_out;
    // 1800 workgroups of 512 threads: one per (oh, h-pair).
    psa_collect_kernel<<<dim3(1800), dim3(512), 0, stream>>>(x, out);
}

// Round 8
// 30.960 us; speedup vs baseline: 1.0634x; 1.0634x over previous
//
#include <hip/hip_runtime.h>

// PSANet COLLECT forward, N=1, H=W=60.
//   out[oh*60+ow][h][w] = x[(oh+59-h)*119 + (ow+59-w)][h][w]
//
// One WG per (oh, h-QUAD) -- 900 WGs x 1024 threads. For each of 4 rows
// h = h0+hh: slab a = oh+59-h; load trimmed parallelogram rows
// (b, w in [max(0,59-b), min(60,119-b))) and scatter compactly into
// lds[hh][ow*60+w], ow = b+w-59 (bijective). LDS 57.6 KB.
// Occupancy: 2 WGs/CU (LDS 115.2/160) x 16 waves = 32 waves/CU (FULL).
// Phase 2: contiguous float4 LDS reads; 960 B contiguous stores per
// output channel (4 h-rows) -> half the partial-line write boundaries
// of the 480 B version. Linear block order, h-quad innermost: WGs
// sharing write-boundary lines are dispatch-adjacent (L2 merge).

#define CH_STRIDE 3600   // H*W floats per channel

typedef float f32x4 __attribute__((ext_vector_type(4)));

__global__ __launch_bounds__(1024) void psa_collect_kernel(
    const float* __restrict__ x, float* __restrict__ out) {

    __shared__ float lds[4][3600];    // 57.6 KB, compact parallelograms

    const int l   = blockIdx.x;       // oh*15 + hq
    const int oh  = l / 15;           // [0,60)
    const int hq  = l - oh * 15;      // [0,15)
    const int h0  = hq * 4;
    const int tid = threadIdx.x;

    // ---- Phase 1: global -> compact LDS (trimmed parallelogram) ----
    for (int hh = 0; hh < 4; ++hh) {
        const int h = h0 + hh;
        const int a = oh + 59 - h;                  // channel-grid row
        const float* src = x + (size_t)a * 119 * CH_STRIDE + h * 60;
        for (int t = tid; t < 119 * 15; t += 1024) {
            const int b  = t / 15;                  // channel-grid col
            const int j4 = (t - b * 15) * 4;        // first w of this float4
            const int w0 = (b < 59) ? (59 - b) : 0;
            const int w1 = (b < 59) ? 60 : (119 - b);
            if (j4 < w1 && j4 + 4 > w0) {
                const float4 v =
                    *reinterpret_cast<const float4*>(src + (size_t)b * CH_STRIDE + j4);
                const float* ve = reinterpret_cast<const float*>(&v);
#pragma unroll
                for (int e = 0; e < 4; ++e) {
                    const int w = j4 + e;
                    const int d = b + w - 59;       // = ow, in [0,60) iff used
                    if ((unsigned)d < 60u) lds[hh][d * 60 + w] = ve[e];
                }
            }
        }
    }
    __syncthreads();

    // ---- Phase 2: LDS -> global, 960 B contiguous per output channel ----
    // m enumerates 3600 float4s: channel ow = m/60, r = m%60 -> hh = r/15,
    // j4 = (r%15)*4. Consecutive m = consecutive addresses within the
    // 960 B per-channel block (coalesced).
    float* dst = out + (size_t)(oh * 60) * CH_STRIDE + h0 * 60;
    for (int m = tid; m < 3600; m += 1024) {
        const int ow = m / 60;
        const int r  = m - ow * 60;                 // 0..59: (hh, j4)
        const int hh = r / 15;
        const int j4 = (r - hh * 15) * 4;
        const f32x4 v = *reinterpret_cast<const f32x4*>(&lds[hh][ow * 60 + j4]);
        *reinterpret_cast<f32x4*>(dst + (size_t)ow * CH_STRIDE + hh * 60 + j4) = v;
    }
}

extern "C" void kernel_launch(void* const* d_in, const int* in_sizes, int n_in,
                              void* d_out, int out_size, void* d_ws, size_t ws_size,
                              hipStream_t stream) {
    const float* x = (const float*)d_in[0];
    float* out = (float*)d_out;
    // 900 workgroups of 1024 threads: one per (oh, h-quad).
    psa_collect_kernel<<<dim3(900), dim3(1024), 0, stream>>>(x, out);
}

// Round 9
// 30.530 us; speedup vs baseline: 1.0784x; 1.0141x over previous
//
#include <hip/hip_runtime.h>

// PSANet COLLECT forward, N=1, H=W=60.  (BEST variant — R5 restored)
//   out[oh*60+ow][h][w] = x[(oh+59-h)*119 + (ow+59-w)][h][w]
//
// One WG per (oh, h-pair) -- 1800 WGs, 512 threads each.
// For each h: slab a = oh+59-h, load trimmed parallelogram rows
// (b, w in [max(0,59-b), min(60,119-b))) and scatter COMPACTLY into
// lds[hh][ow*60+w], ow = b+w-59 (bijective). LDS 28.8 KB.
// Occupancy: 512 thr = 8 waves/WG; 4 WGs/CU -> 32 waves/CU (full).
// Phase 2: contiguous float4 LDS reads, 480 B contiguous stores per
// output channel. XCD-chunked swizzle (1800 = 8*225, bijective).
//
// Measured 29.94 us. Roofline: ~160 MB moved (105-110 read line floor
// + 52 write) -> 25.4 us at 6.3 TB/s stream; scattered ~121 B read
// segments cap effective BW at ~84% of stream -> this is the practical
// floor. Occupancy/L2-tiling/MLP/write-length levers all null or neg.

#define CH_STRIDE 3600   // H*W floats per channel

__global__ __launch_bounds__(512) void psa_collect_kernel(
    const float* __restrict__ x, float* __restrict__ out) {

    __shared__ float lds[2][3600];    // 28.8 KB, compact parallelogram

    // XCD-chunked bijective swizzle: 1800 = 8 * 225.
    int l = blockIdx.x;
    l = (l & 7) * 225 + (l >> 3);
    const int oh = l / 30;            // [0,60)
    const int hp = l - oh * 30;       // [0,30)
    const int h0 = hp * 2;
    const int tid = threadIdx.x;

    // ---- Phase 1: global -> compact LDS (trimmed parallelogram) ----
    for (int hh = 0; hh < 2; ++hh) {
        const int h = h0 + hh;
        const int a = oh + 59 - h;                  // channel-grid row
        const float* src = x + (size_t)a * 119 * CH_STRIDE + h * 60;
        for (int t = tid; t < 119 * 15; t += 512) {
            const int b  = t / 15;                  // channel-grid col
            const int j4 = (t - b * 15) * 4;        // first w of this float4
            const int w0 = (b < 59) ? (59 - b) : 0;
            const int w1 = (b < 59) ? 60 : (119 - b);
            if (j4 < w1 && j4 + 4 > w0) {
                const float4 v =
                    *reinterpret_cast<const float4*>(src + (size_t)b * CH_STRIDE + j4);
                const float* ve = reinterpret_cast<const float*>(&v);
#pragma unroll
                for (int e = 0; e < 4; ++e) {
                    const int w = j4 + e;
                    const int d = b + w - 59;       // = ow, in [0,60) iff used
                    if ((unsigned)d < 60u) lds[hh][d * 60 + w] = ve[e];
                }
            }
        }
    }
    __syncthreads();

    // ---- Phase 2: LDS -> global, 480 B contiguous per output channel ----
    float* dst = out + (size_t)(oh * 60) * CH_STRIDE + h0 * 60;
    for (int m = tid; m < 1800; m += 512) {
        const int ow = m / 30;
        const int r  = m - ow * 30;                 // 0..29: (hh, j4)
        const int hh = r / 15;
        const int j4 = (r - hh * 15) * 4;
        const float4 v = *reinterpret_cast<const float4*>(&lds[hh][ow * 60 + j4]);
        *reinterpret_cast<float4*>(dst + (size_t)ow * CH_STRIDE + hh * 60 + j4) = v;
    }
}

extern "C" void kernel_launch(void* const* d_in, const int* in_sizes, int n_in,
                              void* d_out, int out_size, void* d_ws, size_t ws_size,
                              hipStream_t stream) {
    const float* x = (const float*)d_in[0];
    float* out = (float*)d_out;
    // 1800 workgroups of 512 threads: one per (oh, h-pair).
    psa_collect_kernel<<<dim3(1800), dim3(512), 0, stream>>>(x, out);
}